// Round 5
// baseline (477.740 us; speedup 1.0000x reference)
//
#include <hip/hip_runtime.h>
#include <hip/hip_bf16.h>
#include <math.h>

#define B_   2
#define S_   2048
#define H_   32
#define HKV_ 8
#define HD_  64
#define D_   2048
#define DKV_ 512
#define M_   (B_*S_)

typedef __attribute__((ext_vector_type(8))) short bf16x8;
typedef __attribute__((ext_vector_type(4))) float f32x4;
typedef unsigned short u16;

__device__ __forceinline__ u16 f2bf(float f) {
    union { float f; unsigned u; } v; v.f = f;
    unsigned r = v.u + 0x7fff + ((v.u >> 16) & 1);
    return (u16)(r >> 16);
}
__device__ __forceinline__ unsigned pack_bf16(float lo, float hi) {
    __hip_bfloat162 h = __float22bfloat162_rn(make_float2(lo, hi));
    union { __hip_bfloat162 h; unsigned u; } cv; cv.h = h; return cv.u;
}

// async global->LDS, 16B per lane; LDS dest = uniform base + lane*16
typedef __attribute__((address_space(3))) void lds_void;
typedef const __attribute__((address_space(1))) void g_void;
__device__ __forceinline__ void gl_lds16(const void* g, void* l) {
    __builtin_amdgcn_global_load_lds((g_void*)g, (lds_void*)l, 16, 0, 0);
}

// ---------------- RoPE table: cos/sin(s * 2*pi * theta^(-i/32)) ----------------
__global__ void rope_table_kernel(float* __restrict__ tab) {
    int idx = blockIdx.x * blockDim.x + threadIdx.x;   // 65536 entries
    int s = idx >> 5, i = idx & 31;
    double freq = pow(10000.0, -(double)i / 32.0);
    double ang = (double)s * 6.283185307179586476925286766559 * freq;
    tab[2*idx]   = (float)cos(ang);
    tab[2*idx+1] = (float)sin(ang);
}

// ---------------- fused f32->bf16 conversion: x, Wq, Wk(prescaled), Wv ----------------
// 8-elem units: x 1048576 | Wq 524288 | Wk 131072 | Wv 131072  (total 1835008)
// Wk is pre-scaled by 0.125*log2(e) so attention P = exp2(QK^T) directly.
__global__ void cvt_all_kernel(const float* __restrict__ x,  const float* __restrict__ wq,
                               const float* __restrict__ wk, const float* __restrict__ wv,
                               u16* __restrict__ xb, u16* __restrict__ wall) {
    int i = blockIdx.x * blockDim.x + threadIdx.x;
    if (i >= 1835008) return;
    const float* src; u16* dst;
    float scl = 1.0f;
    size_t e = (size_t)i * 8;
    if (i < 1048576)      { src = x  + e;              dst = xb + e; }
    else if (i < 1572864) { src = wq + (e - 8388608);  dst = wall + (e - 8388608); }
    else if (i < 1703936) { src = wk + (e - 12582912); dst = wall + 4194304 + (e - 12582912); scl = 0.18033688f; }
    else                  { src = wv + (e - 13631488); dst = wall + 5242880 + (e - 13631488); }
    float4 a = *(const float4*)src;
    float4 b = *(const float4*)(src + 4);
    u16 tmp[8] = {f2bf(a.x*scl), f2bf(a.y*scl), f2bf(a.z*scl), f2bf(a.w*scl),
                  f2bf(b.x*scl), f2bf(b.y*scl), f2bf(b.z*scl), f2bf(b.w*scl)};
    *(uint4*)dst = *(const uint4*)tmp;
}

__global__ void cvt_bf16_kernel(const float* __restrict__ src, u16* __restrict__ dst, int n8) {
    int i = blockIdx.x * blockDim.x + threadIdx.x;
    if (i >= n8) return;
    const float4* p = (const float4*)(src + (size_t)i * 8);
    float4 a = p[0], b = p[1];
    u16 tmp[8] = {f2bf(a.x), f2bf(a.y), f2bf(a.z), f2bf(a.w),
                  f2bf(b.x), f2bf(b.y), f2bf(b.z), f2bf(b.w)};
    *(uint4*)(dst + (size_t)i * 8) = *(const uint4*)tmp;
}

// ---------------- V pre-transpose: qkv V-section -> vt[b][kvh][d=64][kv=2048] ----------------
// Global layout bakes the LDS read swizzle: col stored = (kv&~63) | ((kv&63) ^ 8*((d&7)^((d>>3)&7)))
__global__ void vtrans_kernel(const u16* __restrict__ qkv, u16* __restrict__ vt) {
    __shared__ u16 Ts[64*68];
    int t = threadIdx.x;
    int kv0 = blockIdx.x * 64, kvh = blockIdx.y, b = blockIdx.z;
    const u16* src = qkv + (size_t)(b*S_ + kv0) * 3072 + 2560 + kvh*64;
    int r = t >> 3, c = t & 7;
    #pragma unroll
    for (int p = 0; p < 2; ++p) {
        int row = r + 32*p;
        uint4 vv = *(const uint4*)(src + (size_t)row*3072 + c*8);
        u16* dst = &Ts[row*68 + ((c*8) ^ (8*(row & 7)))];
        *(uint2*)dst = make_uint2(((const uint*)&vv)[0], ((const uint*)&vv)[1]);
        *((uint2*)dst + 1) = make_uint2(((const uint*)&vv)[2], ((const uint*)&vv)[3]);
    }
    __syncthreads();
    u16* dstbase = vt + ((size_t)((b*HKV_ + kvh)*64)) * 2048 + kv0;
    #pragma unroll
    for (int p = 0; p < 2; ++p) {
        int d = (t >> 3) + 32*p;
        int g = t & 7;
        u16 tmp[8];
        #pragma unroll
        for (int i = 0; i < 8; ++i)
            tmp[i] = Ts[(8*g + i)*68 + (d ^ (8*i))];
        int sw = 8*((d & 7) ^ ((d >> 3) & 7));
        *(uint4*)(dstbase + (size_t)d*2048 + ((8*g) ^ sw)) = *(const uint4*)tmp;
    }
}

// ============ GEMM (m97): Y[M,N] = X[M,K] @ W[N,K]^T, bf16 in; optional RoPE epi ============
template<bool YF32, bool ROPE>
__launch_bounds__(256, 2)
__global__ void gemm_bt_bf16(const u16* __restrict__ X, const u16* __restrict__ W,
                             void* __restrict__ Y, const float2* __restrict__ tab,
                             int Ndim, int Kdim) {
    __shared__ u16 As[128*32];
    __shared__ u16 Bs[128*32];
    int tid = threadIdx.x;
    int wv = tid >> 6, lane = tid & 63;
    int quad = lane >> 4, lr = lane & 15;
    int wm = wv >> 1, wn = wv & 1;
    int m0 = blockIdx.y * 128, n0 = blockIdx.x * 128;

    int srow = wv*32 + (lane >> 2);
    int scol = (lane & 3) * 8;
    const u16* xp = X + (size_t)(m0 + srow)*Kdim + scol;
    const u16* wp = W + (size_t)(n0 + srow)*Kdim + scol;

    f32x4 acc[4][4] = {};
    for (int k0 = 0; k0 < Kdim; k0 += 32) {
        __syncthreads();
        gl_lds16(xp + k0,                   &As[wv*1024]);
        gl_lds16(xp + 16*(size_t)Kdim + k0, &As[wv*1024 + 512]);
        gl_lds16(wp + k0,                   &Bs[wv*1024]);
        gl_lds16(wp + 16*(size_t)Kdim + k0, &Bs[wv*1024 + 512]);
        __syncthreads();
        bf16x8 af[4], bfr[4];
        #pragma unroll
        for (int t = 0; t < 4; ++t) {
            af[t]  = *(const bf16x8*)(&As[(wm*64 + t*16 + lr)*32 + quad*8]);
            bfr[t] = *(const bf16x8*)(&Bs[(wn*64 + t*16 + lr)*32 + quad*8]);
        }
        #pragma unroll
        for (int mt = 0; mt < 4; ++mt)
            #pragma unroll
            for (int nt = 0; nt < 4; ++nt)
                acc[mt][nt] = __builtin_amdgcn_mfma_f32_16x16x32_bf16(af[mt], bfr[nt], acc[mt][nt], 0, 0, 0);
    }
    #pragma unroll
    for (int mt = 0; mt < 4; ++mt)
        #pragma unroll
        for (int nt = 0; nt < 4; ++nt)
            #pragma unroll
            for (int r = 0; r < 4; ++r) {
                int m = m0 + wm*64 + mt*16 + quad*4 + r;
                int n = n0 + wn*64 + nt*16 + lr;
                float val = acc[mt][nt][r];
                if constexpr (ROPE) {
                    float partner = __shfl_xor(val, 1);
                    if (n < 2560) {  // block-uniform (n0 multiple of 128)
                        float2 cs = tab[(size_t)(m & (S_-1))*32 + ((n >> 1) & 31)];
                        val = fmaf(cs.x, val, ((n & 1) ? cs.y : -cs.y) * partner);
                    }
                }
                if constexpr (YF32) {
                    ((float*)Y)[(size_t)m*Ndim + n] = val;
                } else {
                    float pv = __shfl_xor(val, 1);
                    float lo = (lr & 1) ? pv : val;
                    float hi = (lr & 1) ? val : pv;
                    if (!(lr & 1))
                        *(unsigned*)((u16*)Y + (size_t)m*Ndim + (n & ~1)) = pack_bf16(lo, hi);
                }
            }
}

// ---------------- Flash attention v4 ----------------
// Q-tile 128 (wave w: rows w*32..+32). KV-tile 64. Single barrier/iter.
// K double-buffered via glds (chunk swizzle dc^(kv&7)); V^T double-buffered via glds
// from pre-transposed+pre-swizzled vt buffer. P = exp2(S) (scale folded into Wk),
// row-sums via ones-MFMA, packed u32 P-stores and z-stores.
__launch_bounds__(256, 3)
__global__ void attn_kernel(const u16* __restrict__ qkv, const u16* __restrict__ vt,
                            u16* __restrict__ z) {
    __shared__ u16 Ks[2][64*64];
    __shared__ u16 Vs[2][64*64];
    __shared__ u16 Ps[4][32*64];
    int tid = threadIdx.x;
    int wv = tid >> 6, lane = tid & 63;
    int quad = lane >> 4, lr = lane & 15;
    int b = blockIdx.z, h = blockIdx.y;
    int qt = ((int)gridDim.x - 1) - (int)blockIdx.x;   // long blocks first
    int kvh = h >> 2;
    int qrow_base = qt*128 + wv*32;
    int jmax = 2*qt + 1;

    const u16* qkvb  = qkv + (size_t)(b*S_)*3072;
    const u16* kbase = qkvb + 2048 + kvh*64;
    const u16* vtb   = vt + (size_t)((b*HKV_ + kvh)*64) * 2048;

    int kr  = lane >> 3;
    int dcs = lane & 7;

    // prime j=0 stages
    #pragma unroll
    for (int i = 0; i < 2; ++i) {
        int c = 2*wv + i;
        int rw = c*8 + kr;
        gl_lds16(kbase + (size_t)rw*3072 + (dcs ^ (rw & 7))*8, &Ks[0][c*512]);
        gl_lds16(vtb + (size_t)rw*2048 + dcs*8, &Vs[0][c*512]);
    }

    // Q fragments
    bf16x8 aq[2][2];
    #pragma unroll
    for (int mt = 0; mt < 2; ++mt) {
        const u16* qp = qkvb + (size_t)(qrow_base + mt*16 + lr)*3072 + h*64 + quad*8;
        aq[mt][0] = *(const bf16x8*)(qp);
        aq[mt][1] = *(const bf16x8*)(qp + 32);
    }
    bf16x8 ones;
    #pragma unroll
    for (int i = 0; i < 8; ++i) ones[i] = (short)0x3F80;

    f32x4 oacc[2][4] = {};
    f32x4 lacc[2] = {};

    for (int j = 0; j <= jmax; ++j) {
        int buf = j & 1;
        __syncthreads();   // drains K(j)/V(j) glds; publishes buffers

        if (j < jmax) {    // prefetch next tiles — land during compute(j)
            int kvn = (j+1)*64;
            #pragma unroll
            for (int i = 0; i < 2; ++i) {
                int c = 2*wv + i;
                int rw = c*8 + kr;
                gl_lds16(kbase + (size_t)(kvn + rw)*3072 + (dcs ^ (rw & 7))*8, &Ks[buf^1][c*512]);
                gl_lds16(vtb + (size_t)rw*2048 + kvn + dcs*8, &Vs[buf^1][c*512]);
            }
        }

        int kv0 = j*64;
        if (kv0 < qrow_base + 32) {   // wave has unmasked rows
            // S = Q K^T (K pre-scaled by 0.125*log2e)
            f32x4 sacc[2][4] = {};
            #pragma unroll
            for (int nt = 0; nt < 4; ++nt) {
                int kv = nt*16 + lr;
                #pragma unroll
                for (int ks = 0; ks < 2; ++ks) {
                    bf16x8 bk = *(const bf16x8*)(&Ks[buf][kv*64 + (((ks*4 + quad) ^ (kv & 7))*8)]);
                    sacc[0][nt] = __builtin_amdgcn_mfma_f32_16x16x32_bf16(aq[0][ks], bk, sacc[0][nt], 0, 0, 0);
                    sacc[1][nt] = __builtin_amdgcn_mfma_f32_16x16x32_bf16(aq[1][ks], bk, sacc[1][nt], 0, 0, 0);
                }
            }
            // P = exp2(S); packed pair stores (predicated u32)
            u16* pw = Ps[wv];
            if (kv0 + 63 > qrow_base) {
                #pragma unroll
                for (int mt = 0; mt < 2; ++mt)
                    #pragma unroll
                    for (int nt = 0; nt < 4; ++nt)
                        #pragma unroll
                        for (int r = 0; r < 4; ++r) {
                            int row = mt*16 + quad*4 + r;
                            float p = exp2f(sacc[mt][nt][r]);
                            if (kv0 + nt*16 + lr > qrow_base + row) p = 0.f;
                            float pp = __shfl_xor(p, 1);
                            float lo = (lr & 1) ? pp : p;
                            float hi = (lr & 1) ? p : pp;
                            if (!(lr & 1)) {
                                int col = (nt*16 + lr) ^ (8*(row & 7));
                                *(unsigned*)(&pw[row*64 + col]) = pack_bf16(lo, hi);
                            }
                        }
            } else {
                #pragma unroll
                for (int mt = 0; mt < 2; ++mt)
                    #pragma unroll
                    for (int nt = 0; nt < 4; ++nt)
                        #pragma unroll
                        for (int r = 0; r < 4; ++r) {
                            int row = mt*16 + quad*4 + r;
                            float p = exp2f(sacc[mt][nt][r]);
                            float pp = __shfl_xor(p, 1);
                            float lo = (lr & 1) ? pp : p;
                            float hi = (lr & 1) ? p : pp;
                            if (!(lr & 1)) {
                                int col = (nt*16 + lr) ^ (8*(row & 7));
                                *(unsigned*)(&pw[row*64 + col]) = pack_bf16(lo, hi);
                            }
                        }
            }
            // A-frags of P (same-wave LDS round trip)
            bf16x8 ap[2][2];
            #pragma unroll
            for (int mt = 0; mt < 2; ++mt) {
                int row = mt*16 + lr;
                ap[mt][0] = *(const bf16x8*)(&pw[row*64 + ((quad*8) ^ (8*(lr & 7)))]);
                ap[mt][1] = *(const bf16x8*)(&pw[row*64 + ((32 + quad*8) ^ (8*(lr & 7)))]);
            }
            // O += P V ; l += P 1
            #pragma unroll
            for (int nt = 0; nt < 4; ++nt) {
                int d = nt*16 + lr;
                int g8 = 8*((d & 7) ^ ((d >> 3) & 7));
                bf16x8 bv0 = *(const bf16x8*)(&Vs[buf][d*64 + ((quad*8) ^ g8)]);
                bf16x8 bv1 = *(const bf16x8*)(&Vs[buf][d*64 + ((32 + quad*8) ^ g8)]);
                #pragma unroll
                for (int mt = 0; mt < 2; ++mt) {
                    oacc[mt][nt] = __builtin_amdgcn_mfma_f32_16x16x32_bf16(ap[mt][0], bv0, oacc[mt][nt], 0, 0, 0);
                    oacc[mt][nt] = __builtin_amdgcn_mfma_f32_16x16x32_bf16(ap[mt][1], bv1, oacc[mt][nt], 0, 0, 0);
                }
            }
            #pragma unroll
            for (int mt = 0; mt < 2; ++mt) {
                lacc[mt] = __builtin_amdgcn_mfma_f32_16x16x32_bf16(ap[mt][0], ones, lacc[mt], 0, 0, 0);
                lacc[mt] = __builtin_amdgcn_mfma_f32_16x16x32_bf16(ap[mt][1], ones, lacc[mt], 0, 0, 0);
            }
        }
    }

    // epilogue: divide by l, packed u32 stores
    #pragma unroll
    for (int mt = 0; mt < 2; ++mt)
        #pragma unroll
        for (int nt = 0; nt < 4; ++nt)
            #pragma unroll
            for (int r = 0; r < 4; ++r) {
                int row = qrow_base + mt*16 + quad*4 + r;
                float val = oacc[mt][nt][r] / lacc[mt][r];
                float pv = __shfl_xor(val, 1);
                float lo = (lr & 1) ? pv : val;
                float hi = (lr & 1) ? val : pv;
                if (!(lr & 1))
                    *(unsigned*)(z + (size_t)(b*S_ + row)*D_ + h*64 + nt*16 + (lr & ~1)) = pack_bf16(lo, hi);
            }
}

extern "C" void kernel_launch(void* const* d_in, const int* in_sizes, int n_in,
                              void* d_out, int out_size, void* d_ws, size_t ws_size,
                              hipStream_t stream) {
    const float* x  = (const float*)d_in[0];
    const float* Wq = (const float*)d_in[1];
    const float* Wk = (const float*)d_in[2];
    const float* Wv = (const float*)d_in[3];
    const float* Wo = (const float*)d_in[4];
    float* out = (float*)d_out;
    char* ws = (char*)d_ws;

    // layout (total 55,050,240 B — proven available in rounds 3/4):
    //   [0,16.78M)        xb   -> zbuf after gemm1
    //   [16.78M,29.36M)   wall -> wob (8.39M) + vt (4.19M) after gemm1
    //   [29.36M,29.88M)   tab
    //   [29.88M,55.05M)   qkv (4096 x 3072 bf16)
    u16*    xb   = (u16*)(ws);
    u16*    wall = (u16*)(ws + 16777216);
    u16*    wob  = (u16*)(ws + 16777216);
    u16*    vtb  = (u16*)(ws + 25165824);
    float*  tab  = (float*)(ws + 29360128);
    float2* tab2 = (float2*)(ws + 29360128);
    u16*    qkv  = (u16*)(ws + 29884416);
    u16*    zbuf = (u16*)(ws);

    rope_table_kernel<<<256, 256, 0, stream>>>(tab);
    cvt_all_kernel<<<7168, 256, 0, stream>>>(x, Wq, Wk, Wv, xb, wall);
    gemm_bt_bf16<false, true><<<dim3(24, 32), 256, 0, stream>>>(xb, wall, qkv, tab2, 3072, 2048);
    cvt_bf16_kernel<<<2048, 256, 0, stream>>>(Wo, wob, D_*D_/8);
    vtrans_kernel<<<dim3(32, 8, 2), 256, 0, stream>>>(qkv, vtb);
    attn_kernel<<<dim3(16, 32, 2), 256, 0, stream>>>(qkv, vtb, zbuf);
    gemm_bt_bf16<true, false><<<dim3(16, 32), 256, 0, stream>>>(zbuf, wob, out, tab2, 2048, 2048);
}